// Round 8
// baseline (219.682 us; speedup 1.0000x reference)
//
#include <hip/hip_runtime.h>

#define EPS 1e-3f
#define NPIX  50176   // 16*56*56
#define NOPIX 12544   // 16*28*28

// ws float offsets
#define OFF_ST1W 0        // [32 g][128 c][6] = (s1,t1,w0,w1,w2,w3) fused
#define OFF_S2   24576    // [32][4]
#define OFF_T2   24704    // [32][4]
#define OFF_T3   24832    // [128]
#define OFF_BSUM 24960    // [256]
#define OFF_W3S  25216    // [32 g][4 f][9 kk][4 ci] pre-scaled by s3
#define OFF_U    29824    // [32 g][50176 px] ushort4 (bf16, g-planar)

__device__ __forceinline__ unsigned short f2bf(float f) {
    unsigned u = __float_as_uint(f);
    return (unsigned short)((u + 0x7fffu + ((u >> 16) & 1u)) >> 16);
}
__device__ __forceinline__ float bf2f(unsigned short s) {
    return __uint_as_float(((unsigned)s) << 16);
}

__global__ __launch_bounds__(256)
void prep_kernel(const float* __restrict__ g1, const float* __restrict__ be1,
                 const float* __restrict__ m1, const float* __restrict__ v1,
                 const float* __restrict__ W1, const float* __restrict__ b1,
                 const float* __restrict__ g2, const float* __restrict__ be2,
                 const float* __restrict__ m2, const float* __restrict__ v2,
                 const float* __restrict__ W3, const float* __restrict__ b3,
                 const float* __restrict__ g3, const float* __restrict__ be3,
                 const float* __restrict__ m3, const float* __restrict__ v3,
                 const float* __restrict__ b2, float* __restrict__ ws) {
    int gid = blockIdx.x * 256 + threadIdx.x;
    int stride = gridDim.x * 256;
    // fused table: (s1, t1, W1[c][0..3]) per (g,c)
    for (int i = gid; i < 4096; i += stride) {
        int g = i >> 7, c = i & 127;
        float s = g1[i] * rsqrtf(v1[i] + EPS);
        float t = be1[i] - m1[i] * s;
        float* d = ws + OFF_ST1W + (size_t)i * 6;
        d[0] = s; d[1] = t;
        d[2] = W1[g*512 + c*4 + 0];
        d[3] = W1[g*512 + c*4 + 1];
        d[4] = W1[g*512 + c*4 + 2];
        d[5] = W1[g*512 + c*4 + 3];
    }
    // W3 re-laid f-major, pre-scaled by s3: [g][f][kk][ci]
    for (int i = gid; i < 4608; i += stride) {
        int g = i / 144, rem = i - g*144;
        int f = rem / 36, rem2 = rem - f*36;
        int kk = rem2 >> 2, ci = rem2 & 3;
        int k = g*4 + f;
        float s3 = g3[k] * rsqrtf(v3[k] + EPS);
        ws[OFF_W3S + i] = W3[g*144 + kk*16 + ci*4 + f] * s3;
    }
    if (gid < 128) {
        float s2 = g2[gid] * rsqrtf(v2[gid] + EPS);
        ws[OFF_S2 + gid] = s2;
        ws[OFF_T2 + gid] = be2[gid] + (b1[gid] - m2[gid]) * s2;
        float s3 = g3[gid] * rsqrtf(v3[gid] + EPS);
        ws[OFF_T3 + gid] = be3[gid] + (b3[gid] - m3[gid]) * s3;
    } else if (gid >= 256 && gid < 512) {
        int co = gid - 256;
        float acc = 0.f;
        for (int g = 0; g < 32; ++g) acc += b2[g*256 + co];
        ws[OFF_BSUM + co] = acc;
    }
}

// Stage 1: grid = 784 px-tiles x 4 g-chunks; block 512 = 8 waves.
// Wave w owns ONE group (gchunk*8+w) over the tile's 64 px (lane=px).
// Tables live in LDS, read via same-address broadcast ds_read_b128/b64:
// pure LDS+VALU inner loop, no scalar-cache latency. U bf16 g-planar.
__global__ __launch_bounds__(512)
void stage1_kernel(const float* __restrict__ x,
                   const float* __restrict__ tabs,   // ws
                   float* __restrict__ uout) {       // ws + OFF_U
    __shared__ float4 xs4[2048];   // 32 KB x tile, XOR-swizzled
    __shared__ float  tl[8192];    // 32 KB: [8 g'][128 c][8] (6 used)
    int tid = threadIdx.x;
    int pxtile = blockIdx.x >> 2;
    int gchunk = blockIdx.x & 3;

    const float4* xg = (const float4*)x + (size_t)pxtile * 2048;
    for (int i = tid; i < 2048; i += 512) {
        int p = i >> 5, f4 = i & 31;
        xs4[p*32 + (f4 ^ (p & 31))] = xg[i];
    }
    const float* tsrc = tabs + OFF_ST1W + (size_t)gchunk * 8 * 768;
    for (int i = tid; i < 6144; i += 512) {
        int gp = i / 768, rem = i - gp*768;
        int c = rem / 6, j = rem - c*6;
        tl[gp*1024 + c*8 + j] = tsrc[i];
    }
    __syncthreads();

    int lane = tid & 63;
    int gp = tid >> 6;                       // wave id = group within chunk
    int g = gchunk*8 + gp;
    const float* tg = tl + gp*1024;

    float a0 = 0.f, a1 = 0.f, a2 = 0.f, a3 = 0.f;
    #pragma unroll 1
    for (int ch = 0; ch < 8; ++ch) {
        float xr[16];
        #pragma unroll
        for (int j = 0; j < 4; ++j)
            *(float4*)&xr[4*j] = xs4[lane*32 + ((ch*4 + j) ^ (lane & 31))];
        #pragma unroll
        for (int c = 0; c < 16; ++c) {
            const float* e = tg + (ch*16 + c)*8;
            float4 p0 = *(const float4*)e;       // s,t,w0,w1 (broadcast)
            float2 p1 = *(const float2*)(e + 4); // w2,w3     (broadcast)
            float z = fmaxf(fmaf(xr[c], p0.x, p0.y), 0.f);
            a0 = fmaf(z, p0.z, a0);
            a1 = fmaf(z, p0.w, a1);
            a2 = fmaf(z, p1.x, a2);
            a3 = fmaf(z, p1.y, a3);
        }
    }

    float4 s2v = ((const float4*)(tabs + OFF_S2))[g];  // uniform s_load, once
    float4 t2v = ((const float4*)(tabs + OFF_T2))[g];
    ushort4 o;
    o.x = f2bf(fmaxf(fmaf(a0, s2v.x, t2v.x), 0.f));
    o.y = f2bf(fmaxf(fmaf(a1, s2v.y, t2v.y), 0.f));
    o.z = f2bf(fmaxf(fmaf(a2, s2v.z, t2v.z), 0.f));
    o.w = f2bf(fmaxf(fmaf(a3, s2v.w, t2v.w), 0.f));
    ((ushort4*)uout)[(size_t)g * NPIX + (size_t)pxtile*64 + lane] = o;
}

// Stage 2: block = 8 opx, 256 threads, grid 1568 (≈6 blocks/CU).
// Conv: thread = (oct=tid>>5, opx_l=(tid>>2)&7, f=tid&3), 4 g per thread.
// Phase B transposed: thread = co, 8 opx in regs; W2 read once per block.
__global__ __launch_bounds__(256)
void stage2_kernel(const float* __restrict__ x,
                   const float* __restrict__ W2,     // [128,256]
                   const float* __restrict__ tabs,   // ws
                   const float* __restrict__ U,      // ws + OFF_U (bf16)
                   float* __restrict__ out) {
    __shared__ float w3s[4608];
    __shared__ float t3s[128];
    __shared__ float vs[8 * 132];
    __shared__ float res_s[8];
    int tid = threadIdx.x;
    for (int i = tid; i < 4608; i += 256) w3s[i] = tabs[OFF_W3S + i];
    if (tid < 128) t3s[tid] = tabs[OFF_T3 + tid];
    __syncthreads();

    int opxBase = blockIdx.x * 8;
    // ---- 3x3 stride-2 conv ----
    {
        int oct = tid >> 5, opx_l = (tid >> 2) & 7, f = tid & 3;
        int opx = opxBase + opx_l;
        int b = opx / 784, r = opx - b*784;
        int oh = r / 28, ow = r - oh*28;
        #pragma unroll 1
        for (int gi = 0; gi < 4; ++gi) {
            int g = oct*4 + gi;
            const ushort4* Ug = (const ushort4*)U + (size_t)g * NPIX;
            const float* wg = w3s + g*144 + f*36;
            float a = 0.f;
            #pragma unroll
            for (int kh = 0; kh < 3; ++kh) {
                int ih = 2*oh - 1 + kh;
                if (ih < 0) continue;
                #pragma unroll
                for (int kw = 0; kw < 3; ++kw) {
                    int ic = 2*ow - 1 + kw;
                    if (ic < 0) continue;
                    ushort4 u = Ug[(b*56 + ih)*56 + ic];
                    float4 wv = *(const float4*)(wg + (kh*3 + kw)*4);
                    a = fmaf(bf2f(u.x), wv.x, a);
                    a = fmaf(bf2f(u.y), wv.y, a);
                    a = fmaf(bf2f(u.z), wv.z, a);
                    a = fmaf(bf2f(u.w), wv.w, a);
                }
            }
            int k = g*4 + f;
            vs[opx_l*132 + k] = fmaxf(a + t3s[k], 0.f);
        }
    }
    // ---- residual: res[p] = sum_c x[b, 2oh, 2ow, c] ----
    {
        int p = tid >> 5, l = tid & 31;
        int opx = opxBase + p;
        int b = opx / 784, r = opx - b*784;
        int oh = r / 28, ow = r - oh*28;
        const float* xp = x + (size_t)((b*56 + 2*oh)*56 + 2*ow) * 128;
        float rv = xp[l] + xp[l+32] + xp[l+64] + xp[l+96];
        #pragma unroll
        for (int off = 16; off; off >>= 1) rv += __shfl_down(rv, off, 32);
        if (l == 0) res_s[p] = rv;
    }
    __syncthreads();

    // ---- phase B: out[opx][co] = vs @ W2 + bsum + res, thread = co ----
    int co = tid;
    float acc[8];
    {
        float bs = tabs[OFF_BSUM + co];
        #pragma unroll
        for (int p = 0; p < 8; ++p) acc[p] = bs;
    }
    const float* W2c = W2 + co;
    #pragma unroll 4
    for (int k4 = 0; k4 < 32; ++k4) {
        float w0 = W2c[(4*k4+0)*256];
        float w1 = W2c[(4*k4+1)*256];
        float w2 = W2c[(4*k4+2)*256];
        float w3 = W2c[(4*k4+3)*256];
        #pragma unroll
        for (int p = 0; p < 8; ++p) {
            float4 v = *(const float4*)&vs[p*132 + k4*4];   // broadcast
            acc[p] = fmaf(v.x, w0, acc[p]);
            acc[p] = fmaf(v.y, w1, acc[p]);
            acc[p] = fmaf(v.z, w2, acc[p]);
            acc[p] = fmaf(v.w, w3, acc[p]);
        }
    }
    #pragma unroll
    for (int p = 0; p < 8; ++p)
        out[(size_t)(opxBase + p)*256 + co] = acc[p] + res_s[p];
}

extern "C" void kernel_launch(void* const* d_in, const int* in_sizes, int n_in,
                              void* d_out, int out_size, void* d_ws, size_t ws_size,
                              hipStream_t stream) {
    const float* x   = (const float*)d_in[0];
    const float* g1  = (const float*)d_in[1];
    const float* be1 = (const float*)d_in[2];
    const float* m1  = (const float*)d_in[3];
    const float* v1  = (const float*)d_in[4];
    const float* W1  = (const float*)d_in[5];
    const float* b1  = (const float*)d_in[6];
    const float* g2  = (const float*)d_in[7];
    const float* be2 = (const float*)d_in[8];
    const float* m2  = (const float*)d_in[9];
    const float* v2  = (const float*)d_in[10];
    const float* W3  = (const float*)d_in[11];
    const float* b3  = (const float*)d_in[12];
    const float* g3  = (const float*)d_in[13];
    const float* be3 = (const float*)d_in[14];
    const float* m3  = (const float*)d_in[15];
    const float* v3  = (const float*)d_in[16];
    const float* W2  = (const float*)d_in[17];
    const float* b2  = (const float*)d_in[18];
    float* out = (float*)d_out;
    float* ws  = (float*)d_ws;

    prep_kernel<<<32, 256, 0, stream>>>(g1, be1, m1, v1, W1, b1, g2, be2, m2,
                                        v2, W3, b3, g3, be3, m3, v3, b2, ws);
    stage1_kernel<<<(NPIX / 64) * 4, 512, 0, stream>>>(x, ws, ws + OFF_U);
    stage2_kernel<<<NOPIX / 8, 256, 0, stream>>>(x, W2, ws, ws + OFF_U, out);
}

// Round 9
// 179.837 us; speedup vs baseline: 1.2216x; 1.2216x over previous
//
#include <hip/hip_runtime.h>

#define EPS 1e-3f
#define NPIX  50176   // 16*56*56
#define NOPIX 12544   // 16*28*28

// ws float offsets
#define OFF_T1W  0        // [32 g][16 ch][8 t' + 32 w'] = 20480 (w' = s1*W1, t' = t1/s1)
#define OFF_S2   20480    // [32][4]
#define OFF_T2   20608    // [32][4]
#define OFF_T3   20736    // [128]
#define OFF_BSUM 20864    // [256]
#define OFF_W3S  21120    // [32 g][4 f][9 kk][4 ci] pre-scaled by s3
#define OFF_U    25728    // [32 g][50176 px] ushort4 (bf16, g-planar)

__device__ __forceinline__ unsigned short f2bf(float f) {
    unsigned u = __float_as_uint(f);
    return (unsigned short)((u + 0x7fffu + ((u >> 16) & 1u)) >> 16);
}
__device__ __forceinline__ float bf2f(unsigned short s) {
    return __uint_as_float(((unsigned)s) << 16);
}

__global__ __launch_bounds__(256)
void prep_kernel(const float* __restrict__ g1, const float* __restrict__ be1,
                 const float* __restrict__ m1, const float* __restrict__ v1,
                 const float* __restrict__ W1, const float* __restrict__ b1,
                 const float* __restrict__ g2, const float* __restrict__ be2,
                 const float* __restrict__ m2, const float* __restrict__ v2,
                 const float* __restrict__ W3, const float* __restrict__ b3,
                 const float* __restrict__ g3, const float* __restrict__ be3,
                 const float* __restrict__ m3, const float* __restrict__ v3,
                 const float* __restrict__ b2, float* __restrict__ ws) {
    int gid = blockIdx.x * 256 + threadIdx.x;
    int stride = gridDim.x * 256;
    // T1W: per (g,c): t' = t1/s1 and w'_f = s1*W1[c][f]   (s1 > 0 always)
    for (int i = gid; i < 4096; i += stride) {
        int g = i >> 7, c = i & 127;
        int ch = c >> 3, cc = c & 7;
        float s = g1[i] * rsqrtf(v1[i] + EPS);
        float t = be1[i] - m1[i] * s;
        float* base = ws + OFF_T1W + g*640 + ch*40;
        base[cc] = t / s;
        float* wd = base + 8 + cc*4;
        const float* wsrc = W1 + g*512 + c*4;
        wd[0] = s * wsrc[0];
        wd[1] = s * wsrc[1];
        wd[2] = s * wsrc[2];
        wd[3] = s * wsrc[3];
    }
    // W3 re-laid f-major, pre-scaled by s3: [g][f][kk][ci]
    for (int i = gid; i < 4608; i += stride) {
        int g = i / 144, rem = i - g*144;
        int f = rem / 36, rem2 = rem - f*36;
        int kk = rem2 >> 2, ci = rem2 & 3;
        int k = g*4 + f;
        float s3 = g3[k] * rsqrtf(v3[k] + EPS);
        ws[OFF_W3S + i] = W3[g*144 + kk*16 + ci*4 + f] * s3;
    }
    if (gid < 128) {
        float s2 = g2[gid] * rsqrtf(v2[gid] + EPS);
        ws[OFF_S2 + gid] = s2;
        ws[OFF_T2 + gid] = be2[gid] + (b1[gid] - m2[gid]) * s2;
        float s3 = g3[gid] * rsqrtf(v3[gid] + EPS);
        ws[OFF_T3 + gid] = be3[gid] + (b3[gid] - m3[gid]) * s3;
    } else if (gid >= 256 && gid < 512) {
        int co = gid - 256;
        float acc = 0.f;
        for (int g = 0; g < 32; ++g) acc += b2[g*256 + co];
        ws[OFF_BSUM + co] = acc;
    }
}

// Stage 1: grid = 392 px-tiles (128 px) x 2 group-halves; block 512 = 8 waves.
// Wave owns 2 groups over the 128-px tile (2 sub-tiles of 64 lanes) -> each
// table dword feeds 2x the VALU of R6. Tables: 40-dword contiguous records
// per (g, 8-ch chunk) -> s_load_dwordx8 merging. x fp32 in LDS, XOR-swizzled.
__global__ __launch_bounds__(512)
void stage1_kernel(const float* __restrict__ x,
                   const float* __restrict__ tabs,   // ws
                   float* __restrict__ uout) {       // ws + OFF_U
    __shared__ float4 xs4[4096];   // 64 KB: 128 px x 32 float4, swizzled
    int tid = threadIdx.x;
    int tile  = blockIdx.x >> 1;
    int ghalf = blockIdx.x & 1;

    const float4* xg = (const float4*)x + (size_t)tile * 4096;
    for (int i = tid; i < 4096; i += 512) {
        int p = i >> 5, c4 = i & 31;
        xs4[p*32 + (c4 ^ (p & 31))] = xg[i];
    }
    __syncthreads();

    int lane = tid & 63;
    int gbase = __builtin_amdgcn_readfirstlane(ghalf*16 + (tid >> 6)*2);
    int lsw = lane & 31;

    float accA[2][4], accB[2][4];
    #pragma unroll
    for (int gi = 0; gi < 2; ++gi)
        #pragma unroll
        for (int f = 0; f < 4; ++f) { accA[gi][f] = 0.f; accB[gi][f] = 0.f; }

    #pragma unroll 1
    for (int ch = 0; ch < 16; ++ch) {
        float xa[8], xb[8];
        *(float4*)&xa[0] = xs4[lane*32      + ((2*ch    ) ^ lsw)];
        *(float4*)&xa[4] = xs4[lane*32      + ((2*ch + 1) ^ lsw)];
        *(float4*)&xb[0] = xs4[(64+lane)*32 + ((2*ch    ) ^ lsw)];
        *(float4*)&xb[4] = xs4[(64+lane)*32 + ((2*ch + 1) ^ lsw)];
        #pragma unroll
        for (int gi = 0; gi < 2; ++gi) {
            const float* tb = tabs + OFF_T1W + (gbase + gi)*640 + ch*40;
            #pragma unroll
            for (int cc = 0; cc < 8; ++cc) {
                float tp = tb[cc];                          // SGPR
                float4 w = *(const float4*)(tb + 8 + cc*4); // SGPRs
                float za = fmaxf(xa[cc] + tp, 0.f);
                float zb = fmaxf(xb[cc] + tp, 0.f);
                accA[gi][0] = fmaf(za, w.x, accA[gi][0]);
                accA[gi][1] = fmaf(za, w.y, accA[gi][1]);
                accA[gi][2] = fmaf(za, w.z, accA[gi][2]);
                accA[gi][3] = fmaf(za, w.w, accA[gi][3]);
                accB[gi][0] = fmaf(zb, w.x, accB[gi][0]);
                accB[gi][1] = fmaf(zb, w.y, accB[gi][1]);
                accB[gi][2] = fmaf(zb, w.z, accB[gi][2]);
                accB[gi][3] = fmaf(zb, w.w, accB[gi][3]);
            }
        }
    }

    ushort4* U4 = (ushort4*)uout;
    size_t pxA = (size_t)tile * 128 + lane;
    #pragma unroll
    for (int gi = 0; gi < 2; ++gi) {
        int g = gbase + gi;
        float4 s2v = ((const float4*)(tabs + OFF_S2))[g];
        float4 t2v = ((const float4*)(tabs + OFF_T2))[g];
        ushort4 oa, ob;
        oa.x = f2bf(fmaxf(fmaf(accA[gi][0], s2v.x, t2v.x), 0.f));
        oa.y = f2bf(fmaxf(fmaf(accA[gi][1], s2v.y, t2v.y), 0.f));
        oa.z = f2bf(fmaxf(fmaf(accA[gi][2], s2v.z, t2v.z), 0.f));
        oa.w = f2bf(fmaxf(fmaf(accA[gi][3], s2v.w, t2v.w), 0.f));
        ob.x = f2bf(fmaxf(fmaf(accB[gi][0], s2v.x, t2v.x), 0.f));
        ob.y = f2bf(fmaxf(fmaf(accB[gi][1], s2v.y, t2v.y), 0.f));
        ob.z = f2bf(fmaxf(fmaf(accB[gi][2], s2v.z, t2v.z), 0.f));
        ob.w = f2bf(fmaxf(fmaf(accB[gi][3], s2v.w, t2v.w), 0.f));
        U4[(size_t)g * NPIX + pxA]      = oa;   // 512 B contiguous per wave
        U4[(size_t)g * NPIX + pxA + 64] = ob;
    }
}

// Stage 2: block = 8 opx, 256 threads, grid 1568.
// Conv: thread = (oct=tid>>5, opx_l=(tid>>2)&7, f=tid&3), 4 g per thread.
// Phase B: thread = co, 8 opx in regs; W2 read coalesced once per block.
__global__ __launch_bounds__(256)
void stage2_kernel(const float* __restrict__ x,
                   const float* __restrict__ W2,     // [128,256]
                   const float* __restrict__ tabs,   // ws
                   const float* __restrict__ U,      // ws + OFF_U (bf16)
                   float* __restrict__ out) {
    __shared__ float w3s[4608];
    __shared__ float t3s[128];
    __shared__ float vs[8 * 132];
    __shared__ float res_s[8];
    int tid = threadIdx.x;
    for (int i = tid; i < 4608; i += 256) w3s[i] = tabs[OFF_W3S + i];
    if (tid < 128) t3s[tid] = tabs[OFF_T3 + tid];
    __syncthreads();

    int opxBase = blockIdx.x * 8;
    // ---- 3x3 stride-2 conv ----
    {
        int oct = tid >> 5, opx_l = (tid >> 2) & 7, f = tid & 3;
        int opx = opxBase + opx_l;
        int b = opx / 784, r = opx - b*784;
        int oh = r / 28, ow = r - oh*28;
        #pragma unroll 1
        for (int gi = 0; gi < 4; ++gi) {
            int g = oct*4 + gi;
            const ushort4* Ug = (const ushort4*)U + (size_t)g * NPIX;
            const float* wg = w3s + g*144 + f*36;
            float a = 0.f;
            #pragma unroll
            for (int kh = 0; kh < 3; ++kh) {
                int ih = 2*oh - 1 + kh;
                if (ih < 0) continue;
                #pragma unroll
                for (int kw = 0; kw < 3; ++kw) {
                    int ic = 2*ow - 1 + kw;
                    if (ic < 0) continue;
                    ushort4 u = Ug[(b*56 + ih)*56 + ic];
                    float4 wv = *(const float4*)(wg + (kh*3 + kw)*4);
                    a = fmaf(bf2f(u.x), wv.x, a);
                    a = fmaf(bf2f(u.y), wv.y, a);
                    a = fmaf(bf2f(u.z), wv.z, a);
                    a = fmaf(bf2f(u.w), wv.w, a);
                }
            }
            int k = g*4 + f;
            vs[opx_l*132 + k] = fmaxf(a + t3s[k], 0.f);
        }
    }
    // ---- residual: res[p] = sum_c x[b, 2oh, 2ow, c] ----
    {
        int p = tid >> 5, l = tid & 31;
        int opx = opxBase + p;
        int b = opx / 784, r = opx - b*784;
        int oh = r / 28, ow = r - oh*28;
        const float* xp = x + (size_t)((b*56 + 2*oh)*56 + 2*ow) * 128;
        float rv = xp[l] + xp[l+32] + xp[l+64] + xp[l+96];
        #pragma unroll
        for (int off = 16; off; off >>= 1) rv += __shfl_down(rv, off, 32);
        if (l == 0) res_s[p] = rv;
    }
    __syncthreads();

    // ---- phase B: out[opx][co] = vs @ W2 + bsum + res, thread = co ----
    int co = tid;
    float acc[8];
    {
        float bs = tabs[OFF_BSUM + co];
        #pragma unroll
        for (int p = 0; p < 8; ++p) acc[p] = bs;
    }
    const float* W2c = W2 + co;
    #pragma unroll 4
    for (int k4 = 0; k4 < 32; ++k4) {
        float w0 = W2c[(4*k4+0)*256];
        float w1 = W2c[(4*k4+1)*256];
        float w2 = W2c[(4*k4+2)*256];
        float w3 = W2c[(4*k4+3)*256];
        #pragma unroll
        for (int p = 0; p < 8; ++p) {
            float4 v = *(const float4*)&vs[p*132 + k4*4];   // broadcast
            acc[p] = fmaf(v.x, w0, acc[p]);
            acc[p] = fmaf(v.y, w1, acc[p]);
            acc[p] = fmaf(v.z, w2, acc[p]);
            acc[p] = fmaf(v.w, w3, acc[p]);
        }
    }
    #pragma unroll
    for (int p = 0; p < 8; ++p)
        out[(size_t)(opxBase + p)*256 + co] = acc[p] + res_s[p];
}

extern "C" void kernel_launch(void* const* d_in, const int* in_sizes, int n_in,
                              void* d_out, int out_size, void* d_ws, size_t ws_size,
                              hipStream_t stream) {
    const float* x   = (const float*)d_in[0];
    const float* g1  = (const float*)d_in[1];
    const float* be1 = (const float*)d_in[2];
    const float* m1  = (const float*)d_in[3];
    const float* v1  = (const float*)d_in[4];
    const float* W1  = (const float*)d_in[5];
    const float* b1  = (const float*)d_in[6];
    const float* g2  = (const float*)d_in[7];
    const float* be2 = (const float*)d_in[8];
    const float* m2  = (const float*)d_in[9];
    const float* v2  = (const float*)d_in[10];
    const float* W3  = (const float*)d_in[11];
    const float* b3  = (const float*)d_in[12];
    const float* g3  = (const float*)d_in[13];
    const float* be3 = (const float*)d_in[14];
    const float* m3  = (const float*)d_in[15];
    const float* v3  = (const float*)d_in[16];
    const float* W2  = (const float*)d_in[17];
    const float* b2  = (const float*)d_in[18];
    float* out = (float*)d_out;
    float* ws  = (float*)d_ws;

    prep_kernel<<<32, 256, 0, stream>>>(g1, be1, m1, v1, W1, b1, g2, be2, m2,
                                        v2, W3, b3, g3, be3, m3, v3, b2, ws);
    stage1_kernel<<<(NPIX / 128) * 2, 512, 0, stream>>>(x, ws, ws + OFF_U);
    stage2_kernel<<<NOPIX / 8, 256, 0, stream>>>(x, W2, ws, ws + OFF_U, out);
}